// Round 1
// baseline (430.528 us; speedup 1.0000x reference)
//
#include <hip/hip_runtime.h>
#include <math.h>

#define KEYS (64*64*64)
#define BM 64     // output points per block
#define PAD 68    // padded LDS row in floats (272B: 16B-aligned rows)

// Scatter input point indices into a dense voxel-key -> row map.
__global__ void scatter_kernel(const float* __restrict__ pos, int n,
                               const float* __restrict__ vsp,
                               int* __restrict__ map) {
    int i = blockIdx.x * 256 + threadIdx.x;
    if (i >= n) return;
    float vs = vsp[0];
    int x = (int)floorf(pos[3*i+0] / vs) + 1;
    int y = (int)floorf(pos[3*i+1] / vs) + 1;
    int z = (int)floorf(pos[3*i+2] / vs) + 1;
    map[(z*64 + y)*64 + x] = i;
}

__global__ __launch_bounds__(256) void conv_kernel(
    const float* __restrict__ feats,   // [N,64]
    const float* __restrict__ opos,    // [M,3]
    const float* __restrict__ vsp,     // [1]
    const float* __restrict__ W,       // [27,64,64]
    const float* __restrict__ bias,    // [64]
    const int*   __restrict__ map,     // [64^3]
    float*       __restrict__ out,     // [M,64]
    int M)
{
    __shared__ __align__(16) float Ald[64 * PAD];  // A^T: [cin][point]
    __shared__ __align__(16) float Bld[64 * PAD];  // W tap: [cin][cout]
    __shared__ int cx[BM], cy[BM], cz[BM];

    const int tid = threadIdx.x;
    const int m0  = blockIdx.x * BM;

    // Per-point voxel coords (threads 0..63)
    if (tid < BM) {
        int m = m0 + tid;
        int x = 0, y = 0, z = 0;
        if (m < M) {
            float vs = vsp[0];
            x = (int)floorf(opos[3*m+0] / vs);
            y = (int)floorf(opos[3*m+1] / vs);
            z = (int)floorf(opos[3*m+2] / vs);
        }
        cx[tid] = x; cy[tid] = y; cz[tid] = z;
    }

    const int tp = tid >> 4;   // 0..15: point group (4 points)
    const int tq = tid & 15;   // 0..15: cout group (4 channels)
    const int sp = tid >> 2;   // 0..63: staging point / W row
    const int sb = tid & 3;    // 0..3 : staging 16-float chunk

    float acc[4][4];
    {
        const float4 b = *(const float4*)(bias + tq*4);
        #pragma unroll
        for (int i = 0; i < 4; ++i) {
            acc[i][0] = b.x; acc[i][1] = b.y; acc[i][2] = b.z; acc[i][3] = b.w;
        }
    }

    __syncthreads();  // coords visible

    for (int t = 0; t < 27; ++t) {
        const int dx = t % 3 - 1;
        const int dy = (t / 3) % 3 - 1;
        const int dz = t / 9 - 1;

        // ---- stage A (gathered feature rows, transposed into LDS) ----
        int idx = -1;
        if (m0 + sp < M) {
            int key = ((cz[sp] + dz + 1) * 64 + (cy[sp] + dy + 1)) * 64 + (cx[sp] + dx + 1);
            idx = map[key];
        }
        float4 v0, v1, v2, v3;
        if (idx >= 0) {
            const float4* src = (const float4*)(feats + (size_t)idx * 64 + sb * 16);
            v0 = src[0]; v1 = src[1]; v2 = src[2]; v3 = src[3];
        } else {
            v0 = v1 = v2 = v3 = make_float4(0.f, 0.f, 0.f, 0.f);
        }
        {
            int c = sb * 16;
            Ald[(c+ 0)*PAD + sp] = v0.x; Ald[(c+ 1)*PAD + sp] = v0.y;
            Ald[(c+ 2)*PAD + sp] = v0.z; Ald[(c+ 3)*PAD + sp] = v0.w;
            Ald[(c+ 4)*PAD + sp] = v1.x; Ald[(c+ 5)*PAD + sp] = v1.y;
            Ald[(c+ 6)*PAD + sp] = v1.z; Ald[(c+ 7)*PAD + sp] = v1.w;
            Ald[(c+ 8)*PAD + sp] = v2.x; Ald[(c+ 9)*PAD + sp] = v2.y;
            Ald[(c+10)*PAD + sp] = v2.z; Ald[(c+11)*PAD + sp] = v2.w;
            Ald[(c+12)*PAD + sp] = v3.x; Ald[(c+13)*PAD + sp] = v3.y;
            Ald[(c+14)*PAD + sp] = v3.z; Ald[(c+15)*PAD + sp] = v3.w;
        }

        // ---- stage B (W tap, 16 KB, coalesced) ----
        {
            const float4* wsrc = (const float4*)(W + (size_t)t * 4096 + sp * 64 + sb * 16);
            float4* wdst = (float4*)(Bld + sp * PAD + sb * 16);
            wdst[0] = wsrc[0]; wdst[1] = wsrc[1]; wdst[2] = wsrc[2]; wdst[3] = wsrc[3];
        }
        __syncthreads();

        // ---- 64x64x64 fp32 GEMM, 4x4 register tile per thread ----
        #pragma unroll 8
        for (int k = 0; k < 64; ++k) {
            float4 a = *(const float4*)(Ald + k * PAD + tp * 4);
            float4 b = *(const float4*)(Bld + k * PAD + tq * 4);
            acc[0][0] += a.x*b.x; acc[0][1] += a.x*b.y; acc[0][2] += a.x*b.z; acc[0][3] += a.x*b.w;
            acc[1][0] += a.y*b.x; acc[1][1] += a.y*b.y; acc[1][2] += a.y*b.z; acc[1][3] += a.y*b.w;
            acc[2][0] += a.z*b.x; acc[2][1] += a.z*b.y; acc[2][2] += a.z*b.z; acc[2][3] += a.z*b.w;
            acc[3][0] += a.w*b.x; acc[3][1] += a.w*b.y; acc[3][2] += a.w*b.z; acc[3][3] += a.w*b.w;
        }
        __syncthreads();
    }

    // ---- epilogue ----
    #pragma unroll
    for (int i = 0; i < 4; ++i) {
        int m = m0 + tp * 4 + i;
        if (m < M) {
            float4 o = make_float4(acc[i][0], acc[i][1], acc[i][2], acc[i][3]);
            *(float4*)(out + (size_t)m * 64 + tq * 4) = o;
        }
    }
}

extern "C" void kernel_launch(void* const* d_in, const int* in_sizes, int n_in,
                              void* d_out, int out_size, void* d_ws, size_t ws_size,
                              hipStream_t stream) {
    const float* feats = (const float*)d_in[0];
    const float* ipos  = (const float*)d_in[1];
    const float* opos  = (const float*)d_in[2];
    const float* vsp   = (const float*)d_in[3];
    const float* W     = (const float*)d_in[4];
    const float* bias  = (const float*)d_in[5];

    int N = in_sizes[0] / 64;
    int M = out_size / 64;

    int* map = (int*)d_ws;  // 64^3 int32 = 1 MB

    hipMemsetAsync(map, 0xFF, KEYS * sizeof(int), stream);  // all -1
    scatter_kernel<<<(N + 255) / 256, 256, 0, stream>>>(ipos, N, vsp, map);
    conv_kernel<<<(M + BM - 1) / BM, 256, 0, stream>>>(feats, opos, vsp, W, bias, map,
                                                       (float*)d_out, M);
}

// Round 2
// 199.793 us; speedup vs baseline: 2.1549x; 2.1549x over previous
//
#include <hip/hip_runtime.h>
#include <math.h>

#define KEYS (64*64*64)
#define BM 128          // output points per block
#define LDK 72          // LDS row stride in bf16 elements (144 B = 9*16B -> conflict-free)

typedef __bf16  bf16x8 __attribute__((ext_vector_type(8)));
typedef float  f32x16 __attribute__((ext_vector_type(16)));

// ---- build dense voxel-key -> input-row map ----
__global__ void scatter_kernel(const float* __restrict__ pos, int n,
                               const float* __restrict__ vsp,
                               int* __restrict__ map) {
    int i = blockIdx.x * 256 + threadIdx.x;
    if (i >= n) return;
    float vs = vsp[0];
    int x = (int)floorf(pos[3*i+0] / vs) + 1;
    int y = (int)floorf(pos[3*i+1] / vs) + 1;
    int z = (int)floorf(pos[3*i+2] / vs) + 1;
    map[(z*64 + y)*64 + x] = i;
}

// ---- W [27][cin][cout] fp32 -> Wt [27][cout][cin] bf16 (B^T layout for MFMA) ----
__global__ void convw_kernel(const float* __restrict__ W, __bf16* __restrict__ Wt) {
    int i = blockIdx.x * 256 + threadIdx.x;
    if (i >= 27*64*64) return;
    int t  = i >> 12;
    int r  = i & 4095;
    int ci = r >> 6;
    int co = r & 63;
    Wt[(t << 12) + (co << 6) + ci] = (__bf16)W[i];
}

__global__ __launch_bounds__(256) void conv_kernel(
    const float* __restrict__ feats,   // [N,64] fp32
    const float* __restrict__ opos,    // [M,3]
    const float* __restrict__ vsp,     // [1]
    const __bf16* __restrict__ Wt,     // [27][64cout][64cin] bf16
    const float* __restrict__ bias,    // [64]
    const int*   __restrict__ map,     // [64^3]
    float*       __restrict__ out,     // [M,64]
    int M)
{
    __shared__ __align__(16) __bf16 Ald[BM * LDK];  // 18432 B  [point][cin]
    __shared__ __align__(16) __bf16 Bld[64 * LDK];  //  9216 B  [cout][cin]
    __shared__ int cx[BM], cy[BM], cz[BM];

    const int tid = threadIdx.x;
    const int m0  = blockIdx.x * BM;

    // per-point voxel coords (threads 0..127)
    if (tid < BM) {
        int m = m0 + tid;
        int x = 0, y = 0, z = 0;
        if (m < M) {
            float vs = vsp[0];
            x = (int)floorf(opos[3*m+0] / vs);
            y = (int)floorf(opos[3*m+1] / vs);
            z = (int)floorf(opos[3*m+2] / vs);
        }
        cx[tid] = x; cy[tid] = y; cz[tid] = z;
    }

    // staging roles
    const int sp = tid >> 1;          // 0..127 point row
    const int sh = tid & 1;           // half of the 64-channel row (32 floats)
    const int wr = tid >> 2;          // 0..63 W row (cout)
    const int wc = tid & 3;           // 32B chunk of the 128B W row

    // compute roles
    const int wave  = tid >> 6;       // 0..3
    const int lane  = tid & 63;
    const int nt    = wave & 1;       // n-tile (cout 32-block)
    const int mp    = wave >> 1;      // m-pair (rows mp*64 .. mp*64+63)
    const int lrow  = lane & 31;
    const int halfk = lane >> 5;

    f32x16 acc0, acc1;
    #pragma unroll
    for (int i = 0; i < 16; ++i) { acc0[i] = 0.f; acc1[i] = 0.f; }

    const __bf16* Abase = Ald + (mp*64 + lrow) * LDK + halfk * 8;
    const __bf16* Bbase = Bld + (nt*32 + lrow) * LDK + halfk * 8;
    __bf16* Adst = Ald + sp * LDK + sh * 32;
    __bf16* Bdst = Bld + wr * LDK + wc * 16;

    for (int t = 0; t < 27; ++t) {
        const int dx = t % 3 - 1;
        const int dy = (t / 3) % 3 - 1;
        const int dz = t / 9 - 1;

        __syncthreads();   // coords ready (t=0) / previous compute done

        // ---- stage A: gather feats rows, fp32 -> bf16, [point][cin] ----
        {
            int idx = -1;
            if (m0 + sp < M) {
                int key = ((cz[sp] + dz + 1) * 64 + (cy[sp] + dy + 1)) * 64 + (cx[sp] + dx + 1);
                idx = map[key];
            }
            float4 f0, f1, f2, f3, f4, f5, f6, f7;
            if (idx >= 0) {
                const float4* src = (const float4*)(feats + (size_t)idx * 64 + sh * 32);
                f0 = src[0]; f1 = src[1]; f2 = src[2]; f3 = src[3];
                f4 = src[4]; f5 = src[5]; f6 = src[6]; f7 = src[7];
            } else {
                f0 = f1 = f2 = f3 = f4 = f5 = f6 = f7 = make_float4(0.f,0.f,0.f,0.f);
            }
            bf16x8 c0, c1, c2, c3;
            c0[0]=(__bf16)f0.x; c0[1]=(__bf16)f0.y; c0[2]=(__bf16)f0.z; c0[3]=(__bf16)f0.w;
            c0[4]=(__bf16)f1.x; c0[5]=(__bf16)f1.y; c0[6]=(__bf16)f1.z; c0[7]=(__bf16)f1.w;
            c1[0]=(__bf16)f2.x; c1[1]=(__bf16)f2.y; c1[2]=(__bf16)f2.z; c1[3]=(__bf16)f2.w;
            c1[4]=(__bf16)f3.x; c1[5]=(__bf16)f3.y; c1[6]=(__bf16)f3.z; c1[7]=(__bf16)f3.w;
            c2[0]=(__bf16)f4.x; c2[1]=(__bf16)f4.y; c2[2]=(__bf16)f4.z; c2[3]=(__bf16)f4.w;
            c2[4]=(__bf16)f5.x; c2[5]=(__bf16)f5.y; c2[6]=(__bf16)f5.z; c2[7]=(__bf16)f5.w;
            c3[0]=(__bf16)f6.x; c3[1]=(__bf16)f6.y; c3[2]=(__bf16)f6.z; c3[3]=(__bf16)f6.w;
            c3[4]=(__bf16)f7.x; c3[5]=(__bf16)f7.y; c3[6]=(__bf16)f7.z; c3[7]=(__bf16)f7.w;
            bf16x8* dst = (bf16x8*)Adst;
            dst[0] = c0; dst[1] = c1; dst[2] = c2; dst[3] = c3;
        }

        // ---- stage B: copy bf16 W tap (already transposed) ----
        {
            const float4* wsrc = (const float4*)(Wt + ((size_t)t << 12) + wr * 64 + wc * 16);
            float4* wdst = (float4*)Bdst;
            wdst[0] = wsrc[0]; wdst[1] = wsrc[1];
        }

        __syncthreads();

        // ---- MFMA: 2 m-tiles x 1 n-tile per wave, K=64 in 4 chunks ----
        #pragma unroll
        for (int kc = 0; kc < 4; ++kc) {
            bf16x8 a0 = *(const bf16x8*)(Abase + kc * 16);
            bf16x8 a1 = *(const bf16x8*)(Abase + 32 * LDK + kc * 16);
            bf16x8 b  = *(const bf16x8*)(Bbase + kc * 16);
            acc0 = __builtin_amdgcn_mfma_f32_32x32x16_bf16(a0, b, acc0, 0, 0, 0);
            acc1 = __builtin_amdgcn_mfma_f32_32x32x16_bf16(a1, b, acc1, 0, 0, 0);
        }
    }

    // ---- epilogue: C/D layout col=lane&31, row=(reg&3)+8*(reg>>2)+4*(lane>>5) ----
    const int colo = nt * 32 + lrow;
    const float bv = bias[colo];
    #pragma unroll
    for (int r = 0; r < 16; ++r) {
        int row = (r & 3) + 8 * (r >> 2) + 4 * halfk;
        int m = m0 + mp * 64 + row;
        if (m < M)      out[(size_t)m * 64 + colo]        = acc0[r] + bv;
        if (m + 32 < M) out[(size_t)(m + 32) * 64 + colo] = acc1[r] + bv;
    }
}

extern "C" void kernel_launch(void* const* d_in, const int* in_sizes, int n_in,
                              void* d_out, int out_size, void* d_ws, size_t ws_size,
                              hipStream_t stream) {
    const float* feats = (const float*)d_in[0];
    const float* ipos  = (const float*)d_in[1];
    const float* opos  = (const float*)d_in[2];
    const float* vsp   = (const float*)d_in[3];
    const float* W     = (const float*)d_in[4];
    const float* bias  = (const float*)d_in[5];

    int N = in_sizes[0] / 64;
    int M = out_size / 64;

    int*    map = (int*)d_ws;                       // 1 MB
    __bf16* Wt  = (__bf16*)((char*)d_ws + KEYS * sizeof(int));  // 221 KB

    hipMemsetAsync(map, 0xFF, KEYS * sizeof(int), stream);
    scatter_kernel<<<(N + 255) / 256, 256, 0, stream>>>(ipos, N, vsp, map);
    convw_kernel<<<(27*64*64 + 255) / 256, 256, 0, stream>>>(W, Wt);
    conv_kernel<<<(M + BM - 1) / BM, 256, 0, stream>>>(feats, opos, vsp, Wt, bias, map,
                                                       (float*)d_out, M);
}

// Round 3
// 157.933 us; speedup vs baseline: 2.7260x; 1.2650x over previous
//
#include <hip/hip_runtime.h>
#include <math.h>

// ---- geometry ----
// Grid 50^3, coords shifted +1 -> occupy [1,50] on each axis.
// featsG dense volume: x-stride 64, y,z dims 54. Row = 64 bf16 = 128 B.
#define GY 54
#define GZ 54
#define NROWS (54*54*64)      // 186624 rows

// brick 8x4x4 = 128 output voxels per block; halo 10x6x6 = 360 rows
#define BXV 8
#define BYV 4
#define BZV 4
#define HX 10
#define HY 6
#define HZ 6
#define NH (HX*HY*HZ)         // 360
#define NBX 7                 // ceil(50/8)
#define NBY 13                // ceil(50/4)
#define NBZ 13
#define NBRICK (NBX*NBY*NBZ)  // 1183
#define SLAB 148              // ceil(1183/8) bricks per XCD

#define LDK 72                // LDS row stride (144 B = 9*16B, conflict-free)

typedef __bf16  bf16x8 __attribute__((ext_vector_type(8)));
typedef float  f32x16 __attribute__((ext_vector_type(16)));

// ---- zero-filled dense bf16 feature volume, grid-ordered ----
__global__ void scatter_feats_kernel(const float* __restrict__ feats,
                                     const float* __restrict__ pos,
                                     const float* __restrict__ vsp,
                                     __bf16* __restrict__ featsG, int n) {
    int t = blockIdx.x * 256 + threadIdx.x;
    int i = t >> 2, c = t & 3;
    if (i >= n) return;
    float vs = vsp[0];
    int x = (int)floorf(pos[3*i+0] / vs) + 1;
    int y = (int)floorf(pos[3*i+1] / vs) + 1;
    int z = (int)floorf(pos[3*i+2] / vs) + 1;
    int key = (z * GY + y) * 64 + x;
    const float4* src = (const float4*)(feats + (size_t)i * 64 + c * 16);
    float4 f0 = src[0], f1 = src[1], f2 = src[2], f3 = src[3];
    bf16x8 c0, c1;
    c0[0]=(__bf16)f0.x; c0[1]=(__bf16)f0.y; c0[2]=(__bf16)f0.z; c0[3]=(__bf16)f0.w;
    c0[4]=(__bf16)f1.x; c0[5]=(__bf16)f1.y; c0[6]=(__bf16)f1.z; c0[7]=(__bf16)f1.w;
    c1[0]=(__bf16)f2.x; c1[1]=(__bf16)f2.y; c1[2]=(__bf16)f2.z; c1[3]=(__bf16)f2.w;
    c1[4]=(__bf16)f3.x; c1[5]=(__bf16)f3.y; c1[6]=(__bf16)f3.z; c1[7]=(__bf16)f3.w;
    bf16x8* dst = (bf16x8*)(featsG + (size_t)key * 64 + c * 16);
    dst[0] = c0; dst[1] = c1;
}

// ---- dense voxel-key -> output-row map ----
__global__ void scatter_omap_kernel(const float* __restrict__ pos, int m,
                                    const float* __restrict__ vsp,
                                    int* __restrict__ omap) {
    int i = blockIdx.x * 256 + threadIdx.x;
    if (i >= m) return;
    float vs = vsp[0];
    int x = (int)floorf(pos[3*i+0] / vs) + 1;
    int y = (int)floorf(pos[3*i+1] / vs) + 1;
    int z = (int)floorf(pos[3*i+2] / vs) + 1;
    omap[(z * GY + y) * 64 + x] = i;
}

// ---- W [27][cin][cout] fp32 -> Wt [27][cout][cin] bf16 ----
__global__ void convw_kernel(const float* __restrict__ W, __bf16* __restrict__ Wt) {
    int i = blockIdx.x * 256 + threadIdx.x;
    if (i >= 27*64*64) return;
    int t  = i >> 12;
    int r  = i & 4095;
    int ci = r >> 6;
    int co = r & 63;
    Wt[(t << 12) + (co << 6) + ci] = (__bf16)W[i];
}

__global__ __launch_bounds__(256) void conv_kernel(
    const __bf16* __restrict__ featsG,  // dense volume
    const __bf16* __restrict__ Wt,      // [27][64cout][64cin]
    const float* __restrict__ bias,     // [64]
    const int*   __restrict__ omap,     // dense key -> out row
    float*       __restrict__ out)      // [M,64]
{
    __shared__ __align__(16) __bf16 halo[NH * LDK];   // 51840 B
    __shared__ __align__(16) __bf16 Bld[64 * LDK];    //  9216 B
    __shared__ int obuf[128];                         //   512 B

    const int tid = threadIdx.x;

    // XCD slab swizzle: xcd = bid&7 owns bricks [xcd*SLAB, xcd*SLAB+SLAB)
    int q = (blockIdx.x & 7) * SLAB + (blockIdx.x >> 3);
    if (q >= NBRICK) return;
    const int bx = q % NBX;
    int rem = q / NBX;
    const int by = rem % NBY;
    const int bz = rem / NBY;

    // ---- stage halo: 360 rows x 128 B, contiguous x-runs from featsG ----
    #pragma unroll
    for (int it = 0; it < 12; ++it) {
        int task = it * 256 + tid;
        if (task < NH * 8) {
            int r = task >> 3, c = task & 7;
            int xs = r % HX;
            int t2 = r / HX;
            int ys = t2 % HY;
            int zs = t2 / HY;
            int gkey = ((bz*BZV + zs) * GY + (by*BYV + ys)) * 64 + (bx*BXV + xs);
            *(float4*)(halo + r * LDK + c * 8) =
                *(const float4*)(featsG + (size_t)gkey * 64 + c * 8);
        }
    }
    // ---- stage output-row indices for this brick's 128 voxels ----
    if (tid < 128) {
        int x = tid & 7, y = (tid >> 3) & 3, z = tid >> 5;
        int key = ((bz*BZV + z + 1) * GY + (by*BYV + y + 1)) * 64 + (bx*BXV + x + 1);
        obuf[tid] = omap[key];
    }

    // compute roles
    const int wave  = tid >> 6;       // m-tile 0..3
    const int lane  = tid & 63;
    const int lrow  = lane & 31;
    const int halfk = lane >> 5;
    const int xv = lrow & 7, yv = (lrow >> 3) & 3, zv = wave;
    const int r0 = (zv + 1) * (HX*HY) + (yv + 1) * HX + (xv + 1);
    const int Abase = r0 * LDK + halfk * 8;
    const int Bb0 = lrow * LDK + halfk * 8;
    const int Bb1 = (32 + lrow) * LDK + halfk * 8;

    // W staging role: 512 tasks (64 rows x 8 chunks), 2 per thread
    const int wr0 = tid >> 3,        wc0 = tid & 7;          // task = tid
    const int wr1 = (256 + tid) >> 3, wc1 = tid & 7;         // task = 256+tid

    // preload W tap 0 into registers
    float4 wreg0 = *(const float4*)(Wt + (size_t)wr0 * 64 + wc0 * 8);
    float4 wreg1 = *(const float4*)(Wt + (size_t)wr1 * 64 + wc1 * 8);

    f32x16 acc0, acc1;
    #pragma unroll
    for (int i = 0; i < 16; ++i) { acc0[i] = 0.f; acc1[i] = 0.f; }

    for (int t = 0; t < 27; ++t) {
        // write W tap t (loaded last iteration) into LDS
        *(float4*)(Bld + wr0 * LDK + wc0 * 8) = wreg0;
        *(float4*)(Bld + wr1 * LDK + wc1 * 8) = wreg1;
        __syncthreads();   // B(t) visible (halo/obuf also on t=0)

        // issue W loads for tap t+1 (latency hidden behind compute)
        if (t < 26) {
            const __bf16* wp = Wt + ((size_t)(t + 1) << 12);
            wreg0 = *(const float4*)(wp + wr0 * 64 + wc0 * 8);
            wreg1 = *(const float4*)(wp + wr1 * 64 + wc1 * 8);
        }

        const int dx = t % 3 - 1;
        const int dy = (t / 3) % 3 - 1;
        const int dz = t / 9 - 1;
        const __bf16* Ab = halo + Abase + (dz * (HX*HY) + dy * HX + dx) * LDK;

        #pragma unroll
        for (int kc = 0; kc < 4; ++kc) {
            bf16x8 a  = *(const bf16x8*)(Ab + kc * 16);
            bf16x8 b0 = *(const bf16x8*)(Bld + Bb0 + kc * 16);
            bf16x8 b1 = *(const bf16x8*)(Bld + Bb1 + kc * 16);
            acc0 = __builtin_amdgcn_mfma_f32_32x32x16_bf16(a, b0, acc0, 0, 0, 0);
            acc1 = __builtin_amdgcn_mfma_f32_32x32x16_bf16(a, b1, acc1, 0, 0, 0);
        }
        __syncthreads();   // compute(t) done before B(t+1) overwrite
    }

    // ---- epilogue: C/D layout col=lane&31, row=(reg&3)+8*(reg>>2)+4*(lane>>5) ----
    const int col0 = lrow, col1 = 32 + lrow;
    const float bv0 = bias[col0], bv1 = bias[col1];
    #pragma unroll
    for (int r = 0; r < 16; ++r) {
        int row = (r & 3) + 8 * (r >> 2) + 4 * halfk;
        int orow = obuf[wave * 32 + row];
        if (orow >= 0) {
            out[(size_t)orow * 64 + col0] = acc0[r] + bv0;
            out[(size_t)orow * 64 + col1] = acc1[r] + bv1;
        }
    }
}

extern "C" void kernel_launch(void* const* d_in, const int* in_sizes, int n_in,
                              void* d_out, int out_size, void* d_ws, size_t ws_size,
                              hipStream_t stream) {
    const float* feats = (const float*)d_in[0];
    const float* ipos  = (const float*)d_in[1];
    const float* opos  = (const float*)d_in[2];
    const float* vsp   = (const float*)d_in[3];
    const float* W     = (const float*)d_in[4];
    const float* bias  = (const float*)d_in[5];

    int N = in_sizes[0] / 64;
    int M = out_size / 64;

    // workspace layout
    __bf16* featsG = (__bf16*)d_ws;                          // 23,887,872 B
    int*    omap   = (int*)((char*)d_ws + (size_t)NROWS * 128);        // 746,496 B
    __bf16* Wt     = (__bf16*)((char*)omap + (size_t)NROWS * 4);       // 221,184 B

    hipMemsetAsync(featsG, 0, (size_t)NROWS * 128, stream);
    hipMemsetAsync(omap, 0xFF, (size_t)NROWS * 4, stream);
    scatter_feats_kernel<<<(N*4 + 255) / 256, 256, 0, stream>>>(feats, ipos, vsp, featsG, N);
    scatter_omap_kernel<<<(M + 255) / 256, 256, 0, stream>>>(opos, M, vsp, omap);
    convw_kernel<<<(27*64*64 + 255) / 256, 256, 0, stream>>>(W, Wt);
    conv_kernel<<<8 * SLAB, 256, 0, stream>>>(featsG, Wt, bias, omap, (float*)d_out);
}